// Round 8
// baseline (859.630 us; speedup 1.0000x reference)
//
#include <hip/hip_runtime.h>

typedef unsigned short u16;
typedef __bf16 bf16x8 __attribute__((ext_vector_type(8)));
typedef float f32x4 __attribute__((ext_vector_type(4)));
typedef u16 u16x8 __attribute__((ext_vector_type(8)));
typedef u16 u16x4 __attribute__((ext_vector_type(4)));

__device__ __forceinline__ u16 f2bf(float f) {
    union { float f; unsigned u; } v; v.f = f;
    unsigned r = v.u + 0x7FFFu + ((v.u >> 16) & 1u);
    return (u16)(r >> 16);
}
__device__ __forceinline__ float bf2f(u16 u) {
    union { unsigned u; float f; } v; v.u = ((unsigned)u) << 16; return v.f;
}

#define AS1 __attribute__((address_space(1)))
#define AS3 __attribute__((address_space(3)))
__device__ __forceinline__ void gload_lds16(const void* g, void* l) {
    __builtin_amdgcn_global_load_lds((const AS1 void*)(g), (AS3 void*)(l), 16, 0, 0);
}

// Panel layout (128-row blocks): [panel = R>>7][ktile = k>>5][row = R&127][kk = k&31]
// -> every 128x32 tile is a contiguous 8 KB block; staging is pure contiguous 1KB bursts.

// ---------------- prep: roll(-6,-6) + window partition + cast + PANELIZE ----------------
__global__ __launch_bounds__(256) void prep_x_kernel(const float* __restrict__ x, u16* __restrict__ xw) {
    unsigned i = ((unsigned)blockIdx.x * 256u + threadIdx.x) * 4u;
    int R = (int)(i / 768u); int c = (int)(i % 768u);
    int w = R / 144, nn = R - w * 144;
    int b = w >> 2, wi = w & 3;
    int r = nn / 12, cc = nn - r * 12;
    int sh = (wi >> 1) * 12 + r + 6; if (sh >= 24) sh -= 24;
    int sw = (wi & 1) * 12 + cc + 6; if (sw >= 24) sw -= 24;
    const float* src = x + (((size_t)b * 24 + sh) * 24 + sw) * 768 + c;
    f32x4 v = *(const f32x4*)src;
    u16x4 o; o[0] = f2bf(v[0]); o[1] = f2bf(v[1]); o[2] = f2bf(v[2]); o[3] = f2bf(v[3]);
    size_t idx = ((size_t)(R >> 7) * 24 + (c >> 5)) * 4096 + (R & 127) * 32 + (c & 31);
    *(u16x4*)(xw + idx) = o;
}

// ---------------- weight transpose + cast + panelize: w[K][N] -> wt[panel(n)][kt][n&127][k&31] ----------------
__global__ __launch_bounds__(256) void transpose_cast_kernel(const float* __restrict__ w, u16* __restrict__ wt,
                                                             int K, int N) {
    __shared__ float tile[32][33];
    int tx = threadIdx.x & 31, ty = threadIdx.x >> 5;
    int nb = blockIdx.x * 32, kb = blockIdx.y * 32;
#pragma unroll
    for (int rr = 0; rr < 32; rr += 8) tile[rr + ty][tx] = w[(size_t)(kb + rr + ty) * N + nb + tx];
    __syncthreads();
#pragma unroll
    for (int rr = 0; rr < 32; rr += 8) {
        int n = nb + rr + ty, k = kb + tx;
        wt[((size_t)(n >> 7) * 24 + (k >> 5)) * 4096 + (n & 127) * 32 + (k & 31)] = f2bf(tile[tx][rr + ty]);
    }
}

// ---------------- bias_mat[h][n][m] = bf16(rpb_table[rel_index[n*144+m]][h]) ----------------
__global__ __launch_bounds__(256) void make_bias_kernel(const float* __restrict__ tab, const int* __restrict__ rel,
                                                        u16* __restrict__ bm) {
    int i = blockIdx.x * 256 + threadIdx.x;
    int h = i / 20736, nm = i - h * 20736;
    bm[i] = f2bf(tab[rel[nm] * 24 + h]);
}

// ---------------- 128x128 BK=32, 4 waves, 2 buffers x 16KB, 5 blocks/CU, depth-1 prefetch ----------------
#define FENCE asm volatile("" ::: "memory")
#define BARRIER __builtin_amdgcn_s_barrier()

// tile = contiguous 8 KB at gp; 256 threads x 2 insts x 16 B, linear LDS.
#define STAGE_TILE(gp, ldsoff)                                                                 \
    { const char* srcb = (const char*)(gp);                                                    \
      _Pragma("unroll") for (int j = 0; j < 2; j++) {                                          \
        int off = j * 4096 + t * 16;                                                           \
        gload_lds16(srcb + off, (char*)lds + (ldsoff) + off);                                  \
    } }

template <int EPI>
__global__ __launch_bounds__(256, 5) void gemm128_kernel(const u16* __restrict__ A, const u16* __restrict__ Bt,
                                                         const float* __restrict__ bias,
                                                         u16* __restrict__ o0, u16* __restrict__ o1, u16* __restrict__ o2,
                                                         int Ndim, int Kdim, int nxb, float qscale) {
    __shared__ __align__(16) u16 lds[16384];  // 32 KiB = 2 buffers x 16 KB (A 8K @ +0, B 8K @ +8192)
    const int t = threadIdx.x, lane = t & 63, wv = t >> 6;
    const int wr = wv >> 1, wc = wv & 1;          // 2 x 2 wave grid, 64x64 out per wave
    const int l15 = lane & 15, lg = lane >> 4;
    int nwg = gridDim.x, orig = blockIdx.x;       // bijective XCD swizzle
    int q = nwg >> 3, r = nwg & 7, xcd = orig & 7, loc = orig >> 3;
    int wg = (xcd < r ? xcd * (q + 1) : r * (q + 1) + (xcd - r) * q) + loc;
    int by = wg / nxb, bx = wg - by * nxb;
    const int bm = by << 7, bn = bx << 7;

    f32x4 acc[4][4] = {};
    const int NT = Kdim >> 5;  // 24
    const u16* Ap = A + (size_t)(bm >> 7) * NT * 4096;   // A panel base
    const u16* Bp = Bt + (size_t)(bn >> 7) * NT * 4096;  // B panel base

    // prologue: tile 0 -> buf0
    STAGE_TILE(Ap, 0);
    STAGE_TILE(Bp, 8192);
    asm volatile("s_waitcnt vmcnt(0)" ::: "memory");
    FENCE; BARRIER;

    for (int T = 0; T < NT; ++T) {
        const char* rb = (const char*)lds + (T & 1) * 16384;
        const int nb = ((T + 1) & 1) * 16384;
        if (T + 1 < NT) {
            STAGE_TILE(Ap + (T + 1) * 4096, nb);
            STAGE_TILE(Bp + (T + 1) * 4096, nb + 8192);
        }
        bf16x8 aR[4], bR[4];
#pragma unroll
        for (int mf = 0; mf < 4; mf++)
            aR[mf] = *(const bf16x8*)(rb + (wr * 64 + mf * 16 + l15) * 64 + lg * 16);
#pragma unroll
        for (int nf = 0; nf < 4; nf++)
            bR[nf] = *(const bf16x8*)(rb + 8192 + (wc * 64 + nf * 16 + l15) * 64 + lg * 16);
        __builtin_amdgcn_s_setprio(1);
#pragma unroll
        for (int mf = 0; mf < 4; mf++)
#pragma unroll
            for (int nf = 0; nf < 4; nf++)
                acc[mf][nf] = __builtin_amdgcn_mfma_f32_16x16x32_bf16(aR[mf], bR[nf], acc[mf][nf], 0, 0, 0);
        __builtin_amdgcn_s_setprio(0);
        if (T + 1 < NT) {
            asm volatile("s_waitcnt vmcnt(0)" ::: "memory");  // next tile landed; all waves done reading rb
            FENCE; BARRIER;
        }
    }

    // epilogue
#pragma unroll
    for (int mf = 0; mf < 4; mf++) {
        int Rbase = bm + wr * 64 + mf * 16 + lg * 4;
#pragma unroll
        for (int nf = 0; nf < 4; nf++) {
            int Cg = bn + wc * 64 + nf * 16 + l15;
            float bv = bias[Cg];
            if (EPI == 0) {
                int s = Cg / 768; int rem = Cg - s * 768; int h = rem >> 5; int dd = rem & 31;
#pragma unroll
                for (int rg = 0; rg < 4; rg++) {
                    int R = Rbase + rg;
                    int w2 = R / 144; int nn = R - w2 * 144;
                    float v = acc[mf][nf][rg] + bv;
                    if (s == 0)      o0[((size_t)(w2 * 24 + h) * 144 + nn) * 32 + dd] = f2bf(v * qscale);
                    else if (s == 1) o1[((size_t)(w2 * 24 + h) * 144 + nn) * 32 + dd] = f2bf(v);
                    else             o2[((size_t)(w2 * 24 + h) * 32 + dd) * 144 + nn] = f2bf(v);
                }
            } else {
                // raw16[R*768 + Cg] = bf16(acc + bias)
#pragma unroll
                for (int rg = 0; rg < 4; rg++) {
                    int R = Rbase + rg;
                    o0[(size_t)R * Ndim + Cg] = f2bf(acc[mf][nf][rg] + bv);
                }
            }
        }
    }
}

// ---------------- fused window attention: 1 block per (window, head), 9 waves ----------------
__global__ __launch_bounds__(576) void attn_kernel(const u16* __restrict__ Qg, const u16* __restrict__ Kg,
                                                   const u16* __restrict__ Vg, const u16* __restrict__ bias_mat,
                                                   u16* __restrict__ Ob) {
    __shared__ __align__(16) u16 Qs[144 * 40];
    __shared__ __align__(16) u16 Ks[144 * 40];
    __shared__ __align__(16) u16 Vs[32 * 160];
    __shared__ __align__(16) u16 Ps[144 * 160];
    const int bx = blockIdx.x;
    const int w = bx / 24, h = bx - w * 24;
    const int wi = w & 3, wh = wi >> 1, ww = wi & 1;
    const int t = threadIdx.x, lane = t & 63, wv = t >> 6;
    const int l15 = lane & 15, lg = lane >> 4;
    const size_t base = (size_t)bx * 4608;
    {
        int nn = t >> 2, dd = (t & 3) << 3;
        *(u16x8*)(Qs + nn * 40 + dd) = *(const u16x8*)(Qg + base + nn * 32 + dd);
        *(u16x8*)(Ks + nn * 40 + dd) = *(const u16x8*)(Kg + base + nn * 32 + dd);
        int rv = t / 18, cv = (t - rv * 18) * 8;
        int ba = (rv * 320 + cv * 2) ^ ((rv & 7) << 4);
        *(u16x8*)((char*)Vs + ba) = *(const u16x8*)(Vg + base + rv * 144 + cv);
    }
    u16x8 zz = (u16x8)0;
    if (t < 64)  { int rv = t >> 1, cv = 144 + (t & 1) * 8; int ba = (rv * 320 + cv * 2) ^ ((rv & 7) << 4); *(u16x8*)((char*)Vs + ba) = zz; }
    if (t < 288) { int rv = t >> 1, cv = 144 + (t & 1) * 8; int ba = (rv * 320 + cv * 2) ^ ((rv & 7) << 4); *(u16x8*)((char*)Ps + ba) = zz; }
    __syncthreads();

    f32x4 S[9];
    {
        bf16x8 aq = *(const bf16x8*)(Qs + (wv * 16 + l15) * 40 + lg * 8);
        f32x4 z4 = (f32x4)0.0f;
#pragma unroll
        for (int j = 0; j < 9; j++) {
            bf16x8 bk = *(const bf16x8*)(Ks + (j * 16 + l15) * 40 + lg * 8);
            S[j] = __builtin_amdgcn_mfma_f32_16x16x32_bf16(aq, bk, z4, 0, 0, 0);
        }
    }
    int regm[9];
#pragma unroll
    for (int j = 0; j < 9; j++) {
        int m = j * 16 + l15; int r = m / 12, c = m - r * 12;
        int rid = wh ? (r < 6 ? 1 : 2) : 0;
        int cid = ww ? (c < 6 ? 1 : 2) : 0;
        regm[j] = rid * 3 + cid;
    }
    const u16* bh = bias_mat + h * 20736;
#pragma unroll
    for (int rg = 0; rg < 4; rg++) {
        int n = wv * 16 + lg * 4 + rg;
        int r = n / 12, c = n - r * 12;
        int rid = wh ? (r < 6 ? 1 : 2) : 0;
        int cid = ww ? (c < 6 ? 1 : 2) : 0;
        int regn = rid * 3 + cid;
        const u16* bhn = bh + n * 144;
        float mx = -1e30f;
#pragma unroll
        for (int j = 0; j < 9; j++) {
            float v = S[j][rg] + bf2f(bhn[j * 16 + l15]);
            if (regn != regm[j]) v -= 100.0f;
            S[j][rg] = v;
            mx = fmaxf(mx, v);
        }
#pragma unroll
        for (int d = 1; d < 16; d <<= 1) mx = fmaxf(mx, __shfl_xor(mx, d));
        float sum = 0.0f;
#pragma unroll
        for (int j = 0; j < 9; j++) { float e = __expf(S[j][rg] - mx); S[j][rg] = e; sum += e; }
#pragma unroll
        for (int d = 1; d < 16; d <<= 1) sum += __shfl_xor(sum, d);
        float inv = 1.0f / sum;
#pragma unroll
        for (int j = 0; j < 9; j++) {
            int ba = (n * 320 + (j * 16 + l15) * 2) ^ ((n & 7) << 4);
            *(u16*)((char*)Ps + ba) = f2bf(S[j][rg] * inv);
        }
    }
    __syncthreads();
    f32x4 o0 = (f32x4)0.0f, o1 = (f32x4)0.0f;
#pragma unroll
    for (int ks = 0; ks < 5; ks++) {
        int k2 = (ks * 32 + lg * 8) * 2;
        int ra = wv * 16 + l15;
        bf16x8 ap = *(const bf16x8*)((char*)Ps + ((ra * 320 + k2) ^ ((ra & 7) << 4)));
        int rv0 = l15, rv1 = 16 + l15;
        bf16x8 b0 = *(const bf16x8*)((char*)Vs + ((rv0 * 320 + k2) ^ ((rv0 & 7) << 4)));
        bf16x8 b1 = *(const bf16x8*)((char*)Vs + ((rv1 * 320 + k2) ^ ((rv1 & 7) << 4)));
        o0 = __builtin_amdgcn_mfma_f32_16x16x32_bf16(ap, b0, o0, 0, 0, 0);
        o1 = __builtin_amdgcn_mfma_f32_16x16x32_bf16(ap, b1, o1, 0, 0, 0);
    }
    // write Ob in 128-row PANEL layout for the proj GEMM: R = w*144+n, cols h*32 + d
#pragma unroll
    for (int rg = 0; rg < 4; rg++) {
        int n = wv * 16 + lg * 4 + rg;
        int R = w * 144 + n;
        size_t idx = ((size_t)(R >> 7) * 24 + h) * 4096 + (R & 127) * 32;
        Ob[idx + l15]      = f2bf(o0[rg]);
        Ob[idx + 16 + l15] = f2bf(o1[rg]);
    }
}

// ---------------- L2 norm (bf16 input) + window-merge + reverse shift ----------------
__global__ __launch_bounds__(256) void norm_kernel(const u16* __restrict__ raw, float* __restrict__ out) {
    int R = blockIdx.x * 4 + (threadIdx.x >> 6);
    int lane = threadIdx.x & 63;
    const u16* src = raw + (size_t)R * 768;
    u16x8 a = *(const u16x8*)(src + lane * 8);        // covers [0,512)
    u16x4 b = *(const u16x4*)(src + 512 + lane * 4);  // covers [512,768)
    float f[12];
#pragma unroll
    for (int k = 0; k < 8; k++) f[k] = bf2f(a[k]);
#pragma unroll
    for (int k = 0; k < 4; k++) f[8 + k] = bf2f(b[k]);
    float ss = 0.0f;
#pragma unroll
    for (int k = 0; k < 12; k++) ss += f[k] * f[k];
#pragma unroll
    for (int d = 1; d < 64; d <<= 1) ss += __shfl_xor(ss, d);
    float inv = 1.0f / sqrtf(ss + 1e-6f);
    int w = R / 144, nn = R - w * 144;
    int bb = w >> 2, wi = w & 3;
    int r = nn / 12, cc = nn - r * 12;
    int oh = (wi >> 1) * 12 + r + 6; if (oh >= 24) oh -= 24;
    int ow = (wi & 1) * 12 + cc + 6; if (ow >= 24) ow -= 24;
    float* dst = out + (((size_t)bb * 24 + oh) * 24 + ow) * 768;
    f32x4 v0, v1, v2;
#pragma unroll
    for (int k = 0; k < 4; k++) { v0[k] = f[k] * inv; v1[k] = f[4 + k] * inv; v2[k] = f[8 + k] * inv; }
    *(f32x4*)(dst + lane * 8) = v0;
    *(f32x4*)(dst + lane * 8 + 4) = v1;
    *(f32x4*)(dst + 512 + lane * 4) = v2;
}

extern "C" void kernel_launch(void* const* d_in, const int* in_sizes, int n_in,
                              void* d_out, int out_size, void* d_ws, size_t ws_size,
                              hipStream_t stream) {
    const float* x      = (const float*)d_in[0];
    const float* qkv_w  = (const float*)d_in[1];
    const float* qkv_b  = (const float*)d_in[2];
    const float* proj_w = (const float*)d_in[3];
    const float* proj_b = (const float*)d_in[4];
    const float* rpb    = (const float*)d_in[5];
    const int*   rel    = (const int*)d_in[6];

    char* ws = (char*)d_ws;
    const size_t SZ = 56623104;  // 36864*768*2 bytes
    u16*   xw   = (u16*)(ws);
    u16*   Qb   = (u16*)(ws + SZ);
    u16*   Kb   = (u16*)(ws + 2 * SZ);
    u16*   Vt   = (u16*)(ws + 3 * SZ);
    u16*   Ob   = (u16*)(ws + 4 * SZ);
    u16*   qwt  = (u16*)(ws + 5 * SZ);
    u16*   pwt  = (u16*)(ws + 5 * SZ + 3538944);
    u16*   bm   = (u16*)(ws + 5 * SZ + 3538944 + 1179648);
    u16*   raw16 = (u16*)(ws);  // aliases xw (dead by GEMM2)

    prep_x_kernel<<<27648, 256, 0, stream>>>(x, xw);
    transpose_cast_kernel<<<dim3(72, 24), 256, 0, stream>>>(qkv_w, qwt, 768, 2304);
    transpose_cast_kernel<<<dim3(24, 24), 256, 0, stream>>>(proj_w, pwt, 768, 768);
    make_bias_kernel<<<1944, 256, 0, stream>>>(rpb, rel, bm);

    gemm128_kernel<0><<<5184, 256, 0, stream>>>(xw, qwt, qkv_b, Qb, Kb, Vt,
                                                2304, 768, 18, 0.17677669529663687f);
    attn_kernel<<<6144, 576, 0, stream>>>(Qb, Kb, Vt, bm, Ob);
    gemm128_kernel<1><<<1728, 256, 0, stream>>>(Ob, pwt, proj_b, raw16, nullptr, nullptr,
                                                768, 768, 6, 1.0f);
    norm_kernel<<<9216, 256, 0, stream>>>(raw16, (float*)d_out);
}

// Round 9
// 460.290 us; speedup vs baseline: 1.8676x; 1.8676x over previous
//
#include <hip/hip_runtime.h>

typedef unsigned short u16;
typedef __bf16 bf16x8 __attribute__((ext_vector_type(8)));
typedef float f32x4 __attribute__((ext_vector_type(4)));
typedef u16 u16x8 __attribute__((ext_vector_type(8)));
typedef u16 u16x4 __attribute__((ext_vector_type(4)));

__device__ __forceinline__ u16 f2bf(float f) {
    union { float f; unsigned u; } v; v.f = f;
    unsigned r = v.u + 0x7FFFu + ((v.u >> 16) & 1u);
    return (u16)(r >> 16);
}
__device__ __forceinline__ float bf2f(u16 u) {
    union { unsigned u; float f; } v; v.u = ((unsigned)u) << 16; return v.f;
}

#define AS1 __attribute__((address_space(1)))
#define AS3 __attribute__((address_space(3)))
__device__ __forceinline__ void gload_lds16(const void* g, void* l) {
    __builtin_amdgcn_global_load_lds((const AS1 void*)(g), (AS3 void*)(l), 16, 0, 0);
}

// Panel layout (128-row blocks): [panel = R>>7][ktile = k>>5][row = R&127][kk = k&31]
// -> every 128x32 tile is a contiguous 8 KB block; staging is pure contiguous 1KB bursts.

// ---------------- prep: roll(-6,-6) + window partition + cast + PANELIZE ----------------
__global__ __launch_bounds__(256) void prep_x_kernel(const float* __restrict__ x, u16* __restrict__ xw) {
    unsigned i = ((unsigned)blockIdx.x * 256u + threadIdx.x) * 4u;
    int R = (int)(i / 768u); int c = (int)(i % 768u);
    int w = R / 144, nn = R - w * 144;
    int b = w >> 2, wi = w & 3;
    int r = nn / 12, cc = nn - r * 12;
    int sh = (wi >> 1) * 12 + r + 6; if (sh >= 24) sh -= 24;
    int sw = (wi & 1) * 12 + cc + 6; if (sw >= 24) sw -= 24;
    const float* src = x + (((size_t)b * 24 + sh) * 24 + sw) * 768 + c;
    f32x4 v = *(const f32x4*)src;
    u16x4 o; o[0] = f2bf(v[0]); o[1] = f2bf(v[1]); o[2] = f2bf(v[2]); o[3] = f2bf(v[3]);
    size_t idx = ((size_t)(R >> 7) * 24 + (c >> 5)) * 4096 + (R & 127) * 32 + (c & 31);
    *(u16x4*)(xw + idx) = o;
}

// ---------------- weight transpose + cast + panelize: w[K][N] -> wt[panel(n)][kt][n&127][k&31] ----------------
__global__ __launch_bounds__(256) void transpose_cast_kernel(const float* __restrict__ w, u16* __restrict__ wt,
                                                             int K, int N) {
    __shared__ float tile[32][33];
    int tx = threadIdx.x & 31, ty = threadIdx.x >> 5;
    int nb = blockIdx.x * 32, kb = blockIdx.y * 32;
#pragma unroll
    for (int rr = 0; rr < 32; rr += 8) tile[rr + ty][tx] = w[(size_t)(kb + rr + ty) * N + nb + tx];
    __syncthreads();
#pragma unroll
    for (int rr = 0; rr < 32; rr += 8) {
        int n = nb + rr + ty, k = kb + tx;
        wt[((size_t)(n >> 7) * 24 + (k >> 5)) * 4096 + (n & 127) * 32 + (k & 31)] = f2bf(tile[tx][rr + ty]);
    }
}

// ---------------- bias_mat[h][n][m] = bf16(rpb_table[rel_index[n*144+m]][h]) ----------------
__global__ __launch_bounds__(256) void make_bias_kernel(const float* __restrict__ tab, const int* __restrict__ rel,
                                                        u16* __restrict__ bm) {
    int i = blockIdx.x * 256 + threadIdx.x;
    int h = i / 20736, nm = i - h * 20736;
    bm[i] = f2bf(tab[rel[nm] * 24 + h]);
}

// ------- 128x128 BK=32, 4 waves, 3 buffers x 16KB, 3 blocks/CU, depth-2, PERSISTENT tiles -------
#define FENCE asm volatile("" ::: "memory")
#define BARRIER __builtin_amdgcn_s_barrier()

// tile = contiguous 8 KB at gp; 256 threads x 2 insts x 16 B, linear LDS.
#define STAGE_TILE(gp, ldsoff)                                                                 \
    { const char* srcb = (const char*)(gp);                                                    \
      _Pragma("unroll") for (int j = 0; j < 2; j++) {                                          \
        int off = j * 4096 + t * 16;                                                           \
        gload_lds16(srcb + off, (char*)lds + (ldsoff) + off);                                  \
    } }

template <int EPI>
__global__ __launch_bounds__(256, 3) void gemm128_kernel(const u16* __restrict__ A, const u16* __restrict__ Bt,
                                                         const float* __restrict__ bias,
                                                         u16* __restrict__ o0, u16* __restrict__ o1, u16* __restrict__ o2,
                                                         int Ndim, int Kdim, int nxb, int ntiles, float qscale) {
    __shared__ __align__(16) u16 lds[24576];  // 48 KiB = 3 buffers x 16 KB (A 8K @ +0, B 8K @ +8192)
    const int t = threadIdx.x, lane = t & 63, wv = t >> 6;
    const int wr = wv >> 1, wc = wv & 1;          // 2 x 2 wave grid, 64x64 out per wave
    const int l15 = lane & 15, lg = lane >> 4;
    const int NT = Kdim >> 5;                      // 24 (== 0 mod 3: buffer phase aligns across tiles)
    const int q8 = ntiles >> 3, r8 = ntiles & 7;   // bijective XCD swizzle on tile index

    int tid = blockIdx.x;
    int xcd = tid & 7, loc = tid >> 3;
    int wg = (xcd < r8 ? xcd * (q8 + 1) : r8 * (q8 + 1) + (xcd - r8) * q8) + loc;
    int by = wg / nxb, bx = wg - by * nxb;
    const u16* Ap = A + (size_t)by * NT * 4096;
    const u16* Bp = Bt + (size_t)bx * NT * 4096;

    // prologue (once per block): k-tiles 0,1 of first tile -> bufs 0,1
    STAGE_TILE(Ap, 0);
    STAGE_TILE(Bp, 8192);
    STAGE_TILE(Ap + 4096, 16384);
    STAGE_TILE(Bp + 4096, 16384 + 8192);
    asm volatile("s_waitcnt vmcnt(4)" ::: "memory");  // tile0's 4 loads landed
    FENCE; BARRIER;

    while (true) {
        f32x4 acc[4][4] = {};
        int ntid = tid + (int)gridDim.x;
        bool hasNext = ntid < ntiles;
        int nby = 0, nbx = 0;
        const u16 *Anp = nullptr, *Bnp = nullptr;
        if (hasNext) {
            int nxcd = ntid & 7, nloc = ntid >> 3;
            int nwg = (nxcd < r8 ? nxcd * (q8 + 1) : r8 * (q8 + 1) + (nxcd - r8) * q8) + nloc;
            nby = nwg / nxb; nbx = nwg - nby * nxb;
            Anp = A + (size_t)nby * NT * 4096;
            Bnp = Bt + (size_t)nbx * NT * 4096;
        }
        for (int T = 0; T < NT; ++T) {
            const char* rb = (const char*)lds + (T % 3) * 16384;
            const int sb = ((T + 2) % 3) * 16384;
            bool st = true;
            if (T + 2 < NT) {
                STAGE_TILE(Ap + (T + 2) * 4096, sb);
                STAGE_TILE(Bp + (T + 2) * 4096, sb + 8192);
            } else if (hasNext) {
                int TT = T + 2 - NT;  // 0 or 1: next tile's first k-tiles, seamless pipeline
                STAGE_TILE(Anp + TT * 4096, sb);
                STAGE_TILE(Bnp + TT * 4096, sb + 8192);
            } else st = false;
            bf16x8 aR[4], bR[4];
#pragma unroll
            for (int mf = 0; mf < 4; mf++)
                aR[mf] = *(const bf16x8*)(rb + (wr * 64 + mf * 16 + l15) * 64 + lg * 16);
#pragma unroll
            for (int nf = 0; nf < 4; nf++)
                bR[nf] = *(const bf16x8*)(rb + 8192 + (wc * 64 + nf * 16 + l15) * 64 + lg * 16);
            __builtin_amdgcn_s_setprio(1);
#pragma unroll
            for (int mf = 0; mf < 4; mf++)
#pragma unroll
                for (int nf = 0; nf < 4; nf++)
                    acc[mf][nf] = __builtin_amdgcn_mfma_f32_16x16x32_bf16(aR[mf], bR[nf], acc[mf][nf], 0, 0, 0);
            __builtin_amdgcn_s_setprio(0);
            if (T < NT - 1 || hasNext) {
                if (st) { asm volatile("s_waitcnt vmcnt(4)" ::: "memory"); }
                else    { asm volatile("s_waitcnt vmcnt(0)" ::: "memory"); }
                FENCE; BARRIER;
            }
        }
        // epilogue for tile (by,bx)
        const int bm = by << 7, bn = bx << 7;
#pragma unroll
        for (int mf = 0; mf < 4; mf++) {
            int Rbase = bm + wr * 64 + mf * 16 + lg * 4;
#pragma unroll
            for (int nf = 0; nf < 4; nf++) {
                int Cg = bn + wc * 64 + nf * 16 + l15;
                float bv = bias[Cg];
                if (EPI == 0) {
                    int s = Cg / 768; int rem = Cg - s * 768; int h = rem >> 5; int dd = rem & 31;
#pragma unroll
                    for (int rg = 0; rg < 4; rg++) {
                        int R = Rbase + rg;
                        int w2 = R / 144; int nn = R - w2 * 144;
                        float v = acc[mf][nf][rg] + bv;
                        if (s == 0)      o0[((size_t)(w2 * 24 + h) * 144 + nn) * 32 + dd] = f2bf(v * qscale);
                        else if (s == 1) o1[((size_t)(w2 * 24 + h) * 144 + nn) * 32 + dd] = f2bf(v);
                        else             o2[((size_t)(w2 * 24 + h) * 32 + dd) * 144 + nn] = f2bf(v);
                    }
                } else {
#pragma unroll
                    for (int rg = 0; rg < 4; rg++) {
                        int R = Rbase + rg;
                        o0[(size_t)R * Ndim + Cg] = f2bf(acc[mf][nf][rg] + bv);
                    }
                }
            }
        }
        if (!hasNext) break;
        tid = ntid; by = nby; bx = nbx; Ap = Anp; Bp = Bnp;
    }
}

// ---------------- fused window attention: 1 block per (window, head), 9 waves ----------------
__global__ __launch_bounds__(576) void attn_kernel(const u16* __restrict__ Qg, const u16* __restrict__ Kg,
                                                   const u16* __restrict__ Vg, const u16* __restrict__ bias_mat,
                                                   u16* __restrict__ Ob) {
    __shared__ __align__(16) u16 Qs[144 * 40];
    __shared__ __align__(16) u16 Ks[144 * 40];
    __shared__ __align__(16) u16 Vs[32 * 160];
    __shared__ __align__(16) u16 Ps[144 * 160];
    const int bx = blockIdx.x;
    const int w = bx / 24, h = bx - w * 24;
    const int wi = w & 3, wh = wi >> 1, ww = wi & 1;
    const int t = threadIdx.x, lane = t & 63, wv = t >> 6;
    const int l15 = lane & 15, lg = lane >> 4;
    const size_t base = (size_t)bx * 4608;
    {
        int nn = t >> 2, dd = (t & 3) << 3;
        *(u16x8*)(Qs + nn * 40 + dd) = *(const u16x8*)(Qg + base + nn * 32 + dd);
        *(u16x8*)(Ks + nn * 40 + dd) = *(const u16x8*)(Kg + base + nn * 32 + dd);
        int rv = t / 18, cv = (t - rv * 18) * 8;
        int ba = (rv * 320 + cv * 2) ^ ((rv & 7) << 4);
        *(u16x8*)((char*)Vs + ba) = *(const u16x8*)(Vg + base + rv * 144 + cv);
    }
    u16x8 zz = (u16x8)0;
    if (t < 64)  { int rv = t >> 1, cv = 144 + (t & 1) * 8; int ba = (rv * 320 + cv * 2) ^ ((rv & 7) << 4); *(u16x8*)((char*)Vs + ba) = zz; }
    if (t < 288) { int rv = t >> 1, cv = 144 + (t & 1) * 8; int ba = (rv * 320 + cv * 2) ^ ((rv & 7) << 4); *(u16x8*)((char*)Ps + ba) = zz; }
    __syncthreads();

    f32x4 S[9];
    {
        bf16x8 aq = *(const bf16x8*)(Qs + (wv * 16 + l15) * 40 + lg * 8);
        f32x4 z4 = (f32x4)0.0f;
#pragma unroll
        for (int j = 0; j < 9; j++) {
            bf16x8 bk = *(const bf16x8*)(Ks + (j * 16 + l15) * 40 + lg * 8);
            S[j] = __builtin_amdgcn_mfma_f32_16x16x32_bf16(aq, bk, z4, 0, 0, 0);
        }
    }
    int regm[9];
#pragma unroll
    for (int j = 0; j < 9; j++) {
        int m = j * 16 + l15; int r = m / 12, c = m - r * 12;
        int rid = wh ? (r < 6 ? 1 : 2) : 0;
        int cid = ww ? (c < 6 ? 1 : 2) : 0;
        regm[j] = rid * 3 + cid;
    }
    const u16* bh = bias_mat + h * 20736;
#pragma unroll
    for (int rg = 0; rg < 4; rg++) {
        int n = wv * 16 + lg * 4 + rg;
        int r = n / 12, c = n - r * 12;
        int rid = wh ? (r < 6 ? 1 : 2) : 0;
        int cid = ww ? (c < 6 ? 1 : 2) : 0;
        int regn = rid * 3 + cid;
        const u16* bhn = bh + n * 144;
        float mx = -1e30f;
#pragma unroll
        for (int j = 0; j < 9; j++) {
            float v = S[j][rg] + bf2f(bhn[j * 16 + l15]);
            if (regn != regm[j]) v -= 100.0f;
            S[j][rg] = v;
            mx = fmaxf(mx, v);
        }
#pragma unroll
        for (int d = 1; d < 16; d <<= 1) mx = fmaxf(mx, __shfl_xor(mx, d));
        float sum = 0.0f;
#pragma unroll
        for (int j = 0; j < 9; j++) { float e = __expf(S[j][rg] - mx); S[j][rg] = e; sum += e; }
#pragma unroll
        for (int d = 1; d < 16; d <<= 1) sum += __shfl_xor(sum, d);
        float inv = 1.0f / sum;
#pragma unroll
        for (int j = 0; j < 9; j++) {
            int ba = (n * 320 + (j * 16 + l15) * 2) ^ ((n & 7) << 4);
            *(u16*)((char*)Ps + ba) = f2bf(S[j][rg] * inv);
        }
    }
    __syncthreads();
    f32x4 o0 = (f32x4)0.0f, o1 = (f32x4)0.0f;
#pragma unroll
    for (int ks = 0; ks < 5; ks++) {
        int k2 = (ks * 32 + lg * 8) * 2;
        int ra = wv * 16 + l15;
        bf16x8 ap = *(const bf16x8*)((char*)Ps + ((ra * 320 + k2) ^ ((ra & 7) << 4)));
        int rv0 = l15, rv1 = 16 + l15;
        bf16x8 b0 = *(const bf16x8*)((char*)Vs + ((rv0 * 320 + k2) ^ ((rv0 & 7) << 4)));
        bf16x8 b1 = *(const bf16x8*)((char*)Vs + ((rv1 * 320 + k2) ^ ((rv1 & 7) << 4)));
        o0 = __builtin_amdgcn_mfma_f32_16x16x32_bf16(ap, b0, o0, 0, 0, 0);
        o1 = __builtin_amdgcn_mfma_f32_16x16x32_bf16(ap, b1, o1, 0, 0, 0);
    }
    // write Ob in 128-row PANEL layout for the proj GEMM: R = w*144+n, cols h*32 + d
#pragma unroll
    for (int rg = 0; rg < 4; rg++) {
        int n = wv * 16 + lg * 4 + rg;
        int R = w * 144 + n;
        size_t idx = ((size_t)(R >> 7) * 24 + h) * 4096 + (R & 127) * 32;
        Ob[idx + l15]      = f2bf(o0[rg]);
        Ob[idx + 16 + l15] = f2bf(o1[rg]);
    }
}

// ---------------- L2 norm (bf16 input) + window-merge + reverse shift ----------------
__global__ __launch_bounds__(256) void norm_kernel(const u16* __restrict__ raw, float* __restrict__ out) {
    int R = blockIdx.x * 4 + (threadIdx.x >> 6);
    int lane = threadIdx.x & 63;
    const u16* src = raw + (size_t)R * 768;
    u16x8 a = *(const u16x8*)(src + lane * 8);        // covers [0,512)
    u16x4 b = *(const u16x4*)(src + 512 + lane * 4);  // covers [512,768)
    float f[12];
#pragma unroll
    for (int k = 0; k < 8; k++) f[k] = bf2f(a[k]);
#pragma unroll
    for (int k = 0; k < 4; k++) f[8 + k] = bf2f(b[k]);
    float ss = 0.0f;
#pragma unroll
    for (int k = 0; k < 12; k++) ss += f[k] * f[k];
#pragma unroll
    for (int d = 1; d < 64; d <<= 1) ss += __shfl_xor(ss, d);
    float inv = 1.0f / sqrtf(ss + 1e-6f);
    int w = R / 144, nn = R - w * 144;
    int bb = w >> 2, wi = w & 3;
    int r = nn / 12, cc = nn - r * 12;
    int oh = (wi >> 1) * 12 + r + 6; if (oh >= 24) oh -= 24;
    int ow = (wi & 1) * 12 + cc + 6; if (ow >= 24) ow -= 24;
    float* dst = out + (((size_t)bb * 24 + oh) * 24 + ow) * 768;
    f32x4 v0, v1, v2;
#pragma unroll
    for (int k = 0; k < 4; k++) { v0[k] = f[k] * inv; v1[k] = f[4 + k] * inv; v2[k] = f[8 + k] * inv; }
    *(f32x4*)(dst + lane * 8) = v0;
    *(f32x4*)(dst + lane * 8 + 4) = v1;
    *(f32x4*)(dst + 512 + lane * 4) = v2;
}

extern "C" void kernel_launch(void* const* d_in, const int* in_sizes, int n_in,
                              void* d_out, int out_size, void* d_ws, size_t ws_size,
                              hipStream_t stream) {
    const float* x      = (const float*)d_in[0];
    const float* qkv_w  = (const float*)d_in[1];
    const float* qkv_b  = (const float*)d_in[2];
    const float* proj_w = (const float*)d_in[3];
    const float* proj_b = (const float*)d_in[4];
    const float* rpb    = (const float*)d_in[5];
    const int*   rel    = (const int*)d_in[6];

    char* ws = (char*)d_ws;
    const size_t SZ = 56623104;  // 36864*768*2 bytes
    u16*   xw   = (u16*)(ws);
    u16*   Qb   = (u16*)(ws + SZ);
    u16*   Kb   = (u16*)(ws + 2 * SZ);
    u16*   Vt   = (u16*)(ws + 3 * SZ);
    u16*   Ob   = (u16*)(ws + 4 * SZ);
    u16*   qwt  = (u16*)(ws + 5 * SZ);
    u16*   pwt  = (u16*)(ws + 5 * SZ + 3538944);
    u16*   bm   = (u16*)(ws + 5 * SZ + 3538944 + 1179648);
    u16*   raw16 = (u16*)(ws);  // aliases xw (dead by GEMM2)

    prep_x_kernel<<<27648, 256, 0, stream>>>(x, xw);
    transpose_cast_kernel<<<dim3(72, 24), 256, 0, stream>>>(qkv_w, qwt, 768, 2304);
    transpose_cast_kernel<<<dim3(24, 24), 256, 0, stream>>>(proj_w, pwt, 768, 768);
    make_bias_kernel<<<1944, 256, 0, stream>>>(rpb, rel, bm);

    gemm128_kernel<0><<<768, 256, 0, stream>>>(xw, qwt, qkv_b, Qb, Kb, Vt,
                                               2304, 768, 18, 5184, 0.17677669529663687f);
    attn_kernel<<<6144, 576, 0, stream>>>(Qb, Kb, Vt, bm, Ob);
    gemm128_kernel<1><<<768, 256, 0, stream>>>(Ob, pwt, proj_b, raw16, nullptr, nullptr,
                                               768, 768, 6, 1728, 1.0f);
    norm_kernel<<<9216, 256, 0, stream>>>(raw16, (float*)d_out);
}

// Round 10
// 425.589 us; speedup vs baseline: 2.0199x; 1.0815x over previous
//
#include <hip/hip_runtime.h>

typedef unsigned short u16;
typedef __bf16 bf16x8 __attribute__((ext_vector_type(8)));
typedef float f32x4 __attribute__((ext_vector_type(4)));
typedef u16 u16x8 __attribute__((ext_vector_type(8)));
typedef u16 u16x4 __attribute__((ext_vector_type(4)));
typedef unsigned u32x4 __attribute__((ext_vector_type(4)));

__device__ __forceinline__ u16 f2bf(float f) {
    union { float f; unsigned u; } v; v.f = f;
    unsigned r = v.u + 0x7FFFu + ((v.u >> 16) & 1u);
    return (u16)(r >> 16);
}
__device__ __forceinline__ float bf2f(u16 u) {
    union { unsigned u; float f; } v; v.u = ((unsigned)u) << 16; return v.f;
}
__device__ __forceinline__ unsigned cvt_pk_bf16(float lo, float hi) {
    unsigned r;
    asm("v_cvt_pk_bf16_f32 %0, %1, %2" : "=v"(r) : "v"(lo), "v"(hi));
    return r;
}

#define AS1 __attribute__((address_space(1)))
#define AS3 __attribute__((address_space(3)))
__device__ __forceinline__ void gload_lds16(const void* g, void* l) {
    __builtin_amdgcn_global_load_lds((const AS1 void*)(g), (AS3 void*)(l), 16, 0, 0);
}

// Panel layout (128-row blocks): [panel = R>>7][ktile = k>>5][row = R&127][kk = k&31]

// ---------------- prep: roll(-6,-6) + window partition + cast + PANELIZE ----------------
__global__ __launch_bounds__(256) void prep_x_kernel(const float* __restrict__ x, u16* __restrict__ xw) {
    unsigned i = ((unsigned)blockIdx.x * 256u + threadIdx.x) * 4u;
    int R = (int)(i / 768u); int c = (int)(i % 768u);
    int w = R / 144, nn = R - w * 144;
    int b = w >> 2, wi = w & 3;
    int r = nn / 12, cc = nn - r * 12;
    int sh = (wi >> 1) * 12 + r + 6; if (sh >= 24) sh -= 24;
    int sw = (wi & 1) * 12 + cc + 6; if (sw >= 24) sw -= 24;
    const float* src = x + (((size_t)b * 24 + sh) * 24 + sw) * 768 + c;
    f32x4 v = *(const f32x4*)src;
    u16x4 o; o[0] = f2bf(v[0]); o[1] = f2bf(v[1]); o[2] = f2bf(v[2]); o[3] = f2bf(v[3]);
    size_t idx = ((size_t)(R >> 7) * 24 + (c >> 5)) * 4096 + (R & 127) * 32 + (c & 31);
    *(u16x4*)(xw + idx) = o;
}

// ---------------- weight transpose + cast + panelize ----------------
__global__ __launch_bounds__(256) void transpose_cast_kernel(const float* __restrict__ w, u16* __restrict__ wt,
                                                             int K, int N) {
    __shared__ float tile[32][33];
    int tx = threadIdx.x & 31, ty = threadIdx.x >> 5;
    int nb = blockIdx.x * 32, kb = blockIdx.y * 32;
#pragma unroll
    for (int rr = 0; rr < 32; rr += 8) tile[rr + ty][tx] = w[(size_t)(kb + rr + ty) * N + nb + tx];
    __syncthreads();
#pragma unroll
    for (int rr = 0; rr < 32; rr += 8) {
        int n = nb + rr + ty, k = kb + tx;
        wt[((size_t)(n >> 7) * 24 + (k >> 5)) * 4096 + (n & 127) * 32 + (k & 31)] = f2bf(tile[tx][rr + ty]);
    }
}

// ---------- bias TRANSPOSED: bmT[h][m][n] = bf16(rpb[rel[n*144+m]][h])  (n = q, coalesced) ----------
__global__ __launch_bounds__(256) void make_bias_kernel(const float* __restrict__ tab, const int* __restrict__ rel,
                                                        u16* __restrict__ bm) {
    int i = blockIdx.x * 256 + threadIdx.x;
    int h = i / 20736, mn = i - h * 20736;
    int m = mn / 144, n = mn - m * 144;
    bm[i] = f2bf(tab[rel[n * 144 + m] * 24 + h]);
}

// ------- 128x128 BK=32, 4 waves, 3 buffers x 16KB, 3 blocks/CU, depth-2, PERSISTENT tiles -------
#define FENCE asm volatile("" ::: "memory")
#define BARRIER __builtin_amdgcn_s_barrier()

#define STAGE_TILE(gp, ldsoff)                                                                 \
    { const char* srcb = (const char*)(gp);                                                    \
      _Pragma("unroll") for (int j = 0; j < 2; j++) {                                          \
        int off = j * 4096 + t * 16;                                                           \
        gload_lds16(srcb + off, (char*)lds + (ldsoff) + off);                                  \
    } }

template <int EPI>
__global__ __launch_bounds__(256, 3) void gemm128_kernel(const u16* __restrict__ A, const u16* __restrict__ Bt,
                                                         const float* __restrict__ bias,
                                                         u16* __restrict__ o0, u16* __restrict__ o1, u16* __restrict__ o2,
                                                         int Ndim, int Kdim, int nxb, int ntiles, float qscale) {
    __shared__ __align__(16) u16 lds[24576];
    const int t = threadIdx.x, lane = t & 63, wv = t >> 6;
    const int wr = wv >> 1, wc = wv & 1;
    const int l15 = lane & 15, lg = lane >> 4;
    const int NT = Kdim >> 5;
    const int q8 = ntiles >> 3, r8 = ntiles & 7;

    int tid = blockIdx.x;
    int xcd = tid & 7, loc = tid >> 3;
    int wg = (xcd < r8 ? xcd * (q8 + 1) : r8 * (q8 + 1) + (xcd - r8) * q8) + loc;
    int by = wg / nxb, bx = wg - by * nxb;
    const u16* Ap = A + (size_t)by * NT * 4096;
    const u16* Bp = Bt + (size_t)bx * NT * 4096;

    STAGE_TILE(Ap, 0);
    STAGE_TILE(Bp, 8192);
    STAGE_TILE(Ap + 4096, 16384);
    STAGE_TILE(Bp + 4096, 16384 + 8192);
    asm volatile("s_waitcnt vmcnt(4)" ::: "memory");
    FENCE; BARRIER;

    while (true) {
        f32x4 acc[4][4] = {};
        int ntid = tid + (int)gridDim.x;
        bool hasNext = ntid < ntiles;
        int nby = 0, nbx = 0;
        const u16 *Anp = nullptr, *Bnp = nullptr;
        if (hasNext) {
            int nxcd = ntid & 7, nloc = ntid >> 3;
            int nwg = (nxcd < r8 ? nxcd * (q8 + 1) : r8 * (q8 + 1) + (nxcd - r8) * q8) + nloc;
            nby = nwg / nxb; nbx = nwg - nby * nxb;
            Anp = A + (size_t)nby * NT * 4096;
            Bnp = Bt + (size_t)nbx * NT * 4096;
        }
        for (int T = 0; T < NT; ++T) {
            const char* rb = (const char*)lds + (T % 3) * 16384;
            const int sb = ((T + 2) % 3) * 16384;
            bool st = true;
            if (T + 2 < NT) {
                STAGE_TILE(Ap + (T + 2) * 4096, sb);
                STAGE_TILE(Bp + (T + 2) * 4096, sb + 8192);
            } else if (hasNext) {
                int TT = T + 2 - NT;
                STAGE_TILE(Anp + TT * 4096, sb);
                STAGE_TILE(Bnp + TT * 4096, sb + 8192);
            } else st = false;
            bf16x8 aR[4], bR[4];
#pragma unroll
            for (int mf = 0; mf < 4; mf++)
                aR[mf] = *(const bf16x8*)(rb + (wr * 64 + mf * 16 + l15) * 64 + lg * 16);
#pragma unroll
            for (int nf = 0; nf < 4; nf++)
                bR[nf] = *(const bf16x8*)(rb + 8192 + (wc * 64 + nf * 16 + l15) * 64 + lg * 16);
            __builtin_amdgcn_s_setprio(1);
#pragma unroll
            for (int mf = 0; mf < 4; mf++)
#pragma unroll
                for (int nf = 0; nf < 4; nf++)
                    acc[mf][nf] = __builtin_amdgcn_mfma_f32_16x16x32_bf16(aR[mf], bR[nf], acc[mf][nf], 0, 0, 0);
            __builtin_amdgcn_s_setprio(0);
            if (T < NT - 1 || hasNext) {
                if (st) { asm volatile("s_waitcnt vmcnt(4)" ::: "memory"); }
                else    { asm volatile("s_waitcnt vmcnt(0)" ::: "memory"); }
                FENCE; BARRIER;
            }
        }
        const int bm = by << 7, bn = bx << 7;
#pragma unroll
        for (int mf = 0; mf < 4; mf++) {
            int Rbase = bm + wr * 64 + mf * 16 + lg * 4;
#pragma unroll
            for (int nf = 0; nf < 4; nf++) {
                int Cg = bn + wc * 64 + nf * 16 + l15;
                float bv = bias[Cg];
                if (EPI == 0) {
                    int s = Cg / 768; int rem = Cg - s * 768; int h = rem >> 5; int dd = rem & 31;
#pragma unroll
                    for (int rg = 0; rg < 4; rg++) {
                        int R = Rbase + rg;
                        int w2 = R / 144; int nn = R - w2 * 144;
                        float v = acc[mf][nf][rg] + bv;
                        if (s == 0)      o0[((size_t)(w2 * 24 + h) * 144 + nn) * 32 + dd] = f2bf(v * qscale);
                        else if (s == 1) o1[((size_t)(w2 * 24 + h) * 144 + nn) * 32 + dd] = f2bf(v);
                        else             o2[((size_t)(w2 * 24 + h) * 32 + dd) * 144 + nn] = f2bf(v);
                    }
                } else {
#pragma unroll
                    for (int rg = 0; rg < 4; rg++) {
                        int R = Rbase + rg;
                        o0[(size_t)R * Ndim + Cg] = f2bf(acc[mf][nf][rg] + bv);
                    }
                }
            }
        }
        if (!hasNext) break;
        tid = ntid; by = nby; bx = nbx; Ap = Anp; Bp = Bnp;
    }
}

// ---- fused window attention, SWAPPED operands: block = (window,head), 3 waves x 3 q-stripes ----
// S^T = mfma(A=K, B=Q): lane (l15,lg) holds S[q=s*16+l15][k=16j+4lg+rg]. Softmax per-q needs only
// shfl_xor(16,32). P packed to bf16 (cvt_pk) and shfl-exchanged into PV B-frag; PV: O^T = mfma(A=Vt, B=P^T).
// No Q LDS, no P LDS, one __syncthreads total; 1/sum folded into output write.
__global__ __launch_bounds__(192) void attn_kernel(const u16* __restrict__ Qg, const u16* __restrict__ Kg,
                                                   const u16* __restrict__ Vg, const u16* __restrict__ bmT,
                                                   u16* __restrict__ Ob) {
    __shared__ __align__(16) u16 Ks[144 * 40];
    __shared__ __align__(16) u16 Vs[32 * 160];
    const int bx = blockIdx.x;
    const int w = bx / 24, h = bx - w * 24;
    const int wi = w & 3, wh = wi >> 1, ww = wi & 1;
    const int t = threadIdx.x, lane = t & 63, wv = t >> 6;
    const int l15 = lane & 15, lg = lane >> 4;
    const size_t base = (size_t)bx * 4608;
    // load K -> LDS (stride 40), V -> LDS (swizzled rows), by 192 threads
#pragma unroll
    for (int p = 0; p < 3; p++) {
        int e = t + p * 192;
        int row = e >> 2, cx = (e & 3) << 3;
        *(u16x8*)(Ks + row * 40 + cx) = *(const u16x8*)(Kg + base + row * 32 + cx);
        int rv = e / 18, cv = (e - rv * 18) * 8;
        int ba = (rv * 320 + cv * 2) ^ ((rv & 7) << 4);
        *(u16x8*)((char*)Vs + ba) = *(const u16x8*)(Vg + base + rv * 144 + cv);
    }
    if (t < 64) {
        u16x8 zz = (u16x8)0;
        int rv = t >> 1, cv = 144 + (t & 1) * 8;
        int ba = (rv * 320 + cv * 2) ^ ((rv & 7) << 4);
        *(u16x8*)((char*)Vs + ba) = zz;
    }
    __syncthreads();

    const u16* bh = bmT + h * 20736;
#pragma unroll 1
    for (int it = 0; it < 3; ++it) {
        const int s = wv * 3 + it;
        const int q = s * 16 + l15;
        // Q fragment directly from global (B-operand: lane l15 = q-col, lg = d-chunk)
        bf16x8 aq = *(const bf16x8*)(Qg + base + (size_t)q * 32 + lg * 8);
        f32x4 S[9];
        {
            f32x4 z4 = (f32x4)0.0f;
#pragma unroll
            for (int j = 0; j < 9; j++) {
                bf16x8 bk = *(const bf16x8*)(Ks + (j * 16 + l15) * 40 + lg * 8);
                S[j] = __builtin_amdgcn_mfma_f32_16x16x32_bf16(bk, aq, z4, 0, 0, 0);
            }
        }
        // region id for q (per lane)
        int rq = q / 12, cq = q - rq * 12; int r12 = rq - s * 0; // rq in [0,12) per window? q<144: rq = row in window
        int ridn = wh ? ((rq % 12) < 6 ? 1 : 2) : 0;  // rq is already 0..11 since q<144 -> rq<12
        int cidn = ww ? (cq < 6 ? 1 : 2) : 0;
        int regn = ridn * 3 + cidn;
        (void)r12;
        // bias + mask + max
        float mx = -1e30f;
#pragma unroll
        for (int j = 0; j < 9; j++) {
            const u16* bj = bh + (j * 16 + lg * 4) * 144 + q;
#pragma unroll
            for (int rg = 0; rg < 4; rg++) {
                int k = j * 16 + lg * 4 + rg;
                int rk = k / 12, ck = k - rk * 12;
                int ridm = wh ? (rk < 6 ? 1 : 2) : 0;
                int cidm = ww ? (ck < 6 ? 1 : 2) : 0;
                float v = S[j][rg] + bf2f(bj[rg * 144]);
                if (regn != (ridm * 3 + cidm)) v -= 100.0f;
                S[j][rg] = v;
                mx = fmaxf(mx, v);
            }
        }
        mx = fmaxf(mx, __shfl_xor(mx, 16));
        mx = fmaxf(mx, __shfl_xor(mx, 32));
        float sum = 0.0f;
#pragma unroll
        for (int j = 0; j < 9; j++) {
#pragma unroll
            for (int rg = 0; rg < 4; rg++) { float e = __expf(S[j][rg] - mx); S[j][rg] = e; sum += e; }
        }
        sum += __shfl_xor(sum, 16);
        sum += __shfl_xor(sum, 32);
        float inv = 1.0f / sum;
        // pack P to bf16 pairs: pk[j][0] = {rg0,rg1}, pk[j][1] = {rg2,rg3}; pk[9] = 0
        unsigned pk[10][2];
#pragma unroll
        for (int j = 0; j < 9; j++) {
            pk[j][0] = cvt_pk_bf16(S[j][0], S[j][1]);
            pk[j][1] = cvt_pk_bf16(S[j][2], S[j][3]);
        }
        pk[9][0] = 0; pk[9][1] = 0;
        // PV: O^T = sum_ks mfma(A=Vt rows, B=P^T chunk)
        f32x4 o0 = (f32x4)0.0f, o1 = (f32x4)0.0f;
        const int srcA = 32 * (lg & 1) + l15;   // lane id of source lg' = 2*(lg&1)
        const int srcB = srcA + 16;
        const bool lowj = (lg < 2);
#pragma unroll
        for (int ks = 0; ks < 5; ks++) {
            const int j0 = 2 * ks, j1 = 2 * ks + 1;
            unsigned a0 = __shfl(pk[j0][0], srcA), a1 = __shfl(pk[j0][1], srcA);
            unsigned a2 = __shfl(pk[j0][0], srcB), a3 = __shfl(pk[j0][1], srcB);
            unsigned b0 = __shfl(pk[j1][0], srcA), b1 = __shfl(pk[j1][1], srcA);
            unsigned b2 = __shfl(pk[j1][0], srcB), b3 = __shfl(pk[j1][1], srcB);
            u32x4 pw;
            pw[0] = lowj ? a0 : b0; pw[1] = lowj ? a1 : b1;
            pw[2] = lowj ? a2 : b2; pw[3] = lowj ? a3 : b3;
            bf16x8 pb = *(const bf16x8*)&pw;
            int k2 = (ks * 32 + lg * 8) * 2;
            int rv0 = l15, rv1 = 16 + l15;
            bf16x8 v0 = *(const bf16x8*)((char*)Vs + ((rv0 * 320 + k2) ^ ((rv0 & 7) << 4)));
            bf16x8 v1 = *(const bf16x8*)((char*)Vs + ((rv1 * 320 + k2) ^ ((rv1 & 7) << 4)));
            o0 = __builtin_amdgcn_mfma_f32_16x16x32_bf16(v0, pb, o0, 0, 0, 0);
            o1 = __builtin_amdgcn_mfma_f32_16x16x32_bf16(v1, pb, o1, 0, 0, 0);
        }
        // C layout: col=l15 (=q), row=lg*4+rg (=d within stripe). Write packed u16x4, fold inv.
        int R = w * 144 + q;
        size_t idx = ((size_t)(R >> 7) * 24 + h) * 4096 + (R & 127) * 32 + lg * 4;
        u16x4 w0, w1;
#pragma unroll
        for (int rg = 0; rg < 4; rg++) { w0[rg] = f2bf(o0[rg] * inv); w1[rg] = f2bf(o1[rg] * inv); }
        *(u16x4*)(Ob + idx) = w0;
        *(u16x4*)(Ob + idx + 16) = w1;
    }
}

// ---------------- L2 norm (bf16 input) + window-merge + reverse shift ----------------
__global__ __launch_bounds__(256) void norm_kernel(const u16* __restrict__ raw, float* __restrict__ out) {
    int R = blockIdx.x * 4 + (threadIdx.x >> 6);
    int lane = threadIdx.x & 63;
    const u16* src = raw + (size_t)R * 768;
    u16x8 a = *(const u16x8*)(src + lane * 8);
    u16x4 b = *(const u16x4*)(src + 512 + lane * 4);
    float f[12];
#pragma unroll
    for (int k = 0; k < 8; k++) f[k] = bf2f(a[k]);
#pragma unroll
    for (int k = 0; k < 4; k++) f[8 + k] = bf2f(b[k]);
    float ss = 0.0f;
#pragma unroll
    for (int k = 0; k < 12; k++) ss += f[k] * f[k];
#pragma unroll
    for (int d = 1; d < 64; d <<= 1) ss += __shfl_xor(ss, d);
    float inv = 1.0f / sqrtf(ss + 1e-6f);
    int w = R / 144, nn = R - w * 144;
    int bb = w >> 2, wi = w & 3;
    int r = nn / 12, cc = nn - r * 12;
    int oh = (wi >> 1) * 12 + r + 6; if (oh >= 24) oh -= 24;
    int ow = (wi & 1) * 12 + cc + 6; if (ow >= 24) ow -= 24;
    float* dst = out + (((size_t)bb * 24 + oh) * 24 + ow) * 768;
    f32x4 v0, v1, v2;
#pragma unroll
    for (int k = 0; k < 4; k++) { v0[k] = f[k] * inv; v1[k] = f[4 + k] * inv; v2[k] = f[8 + k] * inv; }
    *(f32x4*)(dst + lane * 8) = v0;
    *(f32x4*)(dst + lane * 8 + 4) = v1;
    *(f32x4*)(dst + 512 + lane * 4) = v2;
}

extern "C" void kernel_launch(void* const* d_in, const int* in_sizes, int n_in,
                              void* d_out, int out_size, void* d_ws, size_t ws_size,
                              hipStream_t stream) {
    const float* x      = (const float*)d_in[0];
    const float* qkv_w  = (const float*)d_in[1];
    const float* qkv_b  = (const float*)d_in[2];
    const float* proj_w = (const float*)d_in[3];
    const float* proj_b = (const float*)d_in[4];
    const float* rpb    = (const float*)d_in[5];
    const int*   rel    = (const int*)d_in[6];

    char* ws = (char*)d_ws;
    const size_t SZ = 56623104;  // 36864*768*2 bytes
    u16*   xw   = (u16*)(ws);
    u16*   Qb   = (u16*)(ws + SZ);
    u16*   Kb   = (u16*)(ws + 2 * SZ);
    u16*   Vt   = (u16*)(ws + 3 * SZ);
    u16*   Ob   = (u16*)(ws + 4 * SZ);
    u16*   qwt  = (u16*)(ws + 5 * SZ);
    u16*   pwt  = (u16*)(ws + 5 * SZ + 3538944);
    u16*   bm   = (u16*)(ws + 5 * SZ + 3538944 + 1179648);
    u16*   raw16 = (u16*)(ws);  // aliases xw (dead by GEMM2)

    prep_x_kernel<<<27648, 256, 0, stream>>>(x, xw);
    transpose_cast_kernel<<<dim3(72, 24), 256, 0, stream>>>(qkv_w, qwt, 768, 2304);
    transpose_cast_kernel<<<dim3(24, 24), 256, 0, stream>>>(proj_w, pwt, 768, 768);
    make_bias_kernel<<<1944, 256, 0, stream>>>(rpb, rel, bm);

    gemm128_kernel<0><<<768, 256, 0, stream>>>(xw, qwt, qkv_b, Qb, Kb, Vt,
                                               2304, 768, 18, 5184, 0.17677669529663687f);
    attn_kernel<<<6144, 192, 0, stream>>>(Qb, Kb, Vt, bm, Ob);
    gemm128_kernel<1><<<768, 256, 0, stream>>>(Ob, pwt, proj_b, raw16, nullptr, nullptr,
                                               768, 768, 6, 1728, 1.0f);
    norm_kernel<<<9216, 256, 0, stream>>>(raw16, (float*)d_out);
}